// Round 3
// baseline (356.331 us; speedup 1.0000x reference)
//
#include <hip/hip_runtime.h>
#include <hip/hip_bf16.h>
#include <math.h>

// ---------------------------------------------------------------------------
// Two-layer GAT (PyG GATConv semantics), fp32 throughout.
//   L1: h1 = x@W1 [30000,256]; att scores per node/head; edge softmax by dst;
//       h = elu(agg + b1)
//   L2: h2 = h@W2 [30000,64]; single head; out = agg + b2
// Softmax max-subtraction is skipped (shift-invariant; |logits| ~ O(1)).
// Graph CSR (by dst) is rebuilt on device every call (deterministic work).
// ---------------------------------------------------------------------------

#define NN 30000
#define NE 480000

static constexpr size_t au(size_t x) { return (x + 255) & ~(size_t)255; }

static constexpr size_t SZ_H1  = (size_t)NN * 256 * 4;
static constexpr size_t SZ_H   = (size_t)NN * 256 * 4;
static constexpr size_t SZ_AS1 = (size_t)NN * 4 * 4;
static constexpr size_t SZ_AS2 = (size_t)NN * 4;
static constexpr size_t SZ_ROW = (size_t)(NN + 1) * 4;
static constexpr size_t SZ_CUR = (size_t)NN * 4;
static constexpr size_t SZ_CSR = (size_t)NE * 4;

static constexpr size_t OFF_H1  = 0;                       // h1, later reused as h2
static constexpr size_t OFF_H   = OFF_H1  + au(SZ_H1);
static constexpr size_t OFF_AS1 = OFF_H   + au(SZ_H);
static constexpr size_t OFF_AD1 = OFF_AS1 + au(SZ_AS1);
static constexpr size_t OFF_AS2 = OFF_AD1 + au(SZ_AS1);
static constexpr size_t OFF_AD2 = OFF_AS2 + au(SZ_AS2);
static constexpr size_t OFF_ROW = OFF_AD2 + au(SZ_AS2);
static constexpr size_t OFF_CUR = OFF_ROW + au(SZ_ROW);
static constexpr size_t OFF_CSR = OFF_CUR + au(SZ_CUR);
// total ~64.9 MB of d_ws

__device__ __forceinline__ float lrelu(float x) { return x > 0.f ? x : 0.2f * x; }
__device__ __forceinline__ float elu1(float x)  { return x > 0.f ? x : expm1f(x); }

// ---------------- CSR build ----------------

__global__ __launch_bounds__(256) void zero_int_kernel(int* __restrict__ p, int n) {
    int i = blockIdx.x * 256 + threadIdx.x;
    if (i < n) p[i] = 0;
}

__global__ __launch_bounds__(256) void copy_int_kernel(const int* __restrict__ a,
                                                       int* __restrict__ b, int n) {
    int i = blockIdx.x * 256 + threadIdx.x;
    if (i < n) b[i] = a[i];
}

__global__ __launch_bounds__(256) void hist_kernel(const int* __restrict__ dst,
                                                   int* __restrict__ counts, int e) {
    int i = blockIdx.x * 256 + threadIdx.x;
    if (i < e) atomicAdd(&counts[dst[i]], 1);
}

// single-block exclusive scan of counts[0..n) -> row_ptr[0..n]
__global__ __launch_bounds__(1024) void scan_kernel(const int* __restrict__ counts,
                                                    int* __restrict__ row_ptr, int n) {
    __shared__ int sdata[1024];
    __shared__ int s_carry;
    int tid = threadIdx.x;
    if (tid == 0) s_carry = 0;
    __syncthreads();
    for (int base = 0; base < n; base += 1024) {
        int i = base + tid;
        int v = (i < n) ? counts[i] : 0;
        sdata[tid] = v;
        __syncthreads();
        for (int off = 1; off < 1024; off <<= 1) {
            int t = (tid >= off) ? sdata[tid - off] : 0;
            __syncthreads();
            sdata[tid] += t;
            __syncthreads();
        }
        int carry = s_carry;
        if (i < n) row_ptr[i] = carry + sdata[tid] - v;   // exclusive
        __syncthreads();
        if (tid == 0) s_carry = carry + sdata[1023];
        __syncthreads();
    }
    if (tid == 0) row_ptr[n] = s_carry;
}

__global__ __launch_bounds__(256) void fill_kernel(const int* __restrict__ src,
                                                   const int* __restrict__ dst,
                                                   int* __restrict__ cursor,
                                                   int* __restrict__ csr_src, int e) {
    int i = blockIdx.x * 256 + threadIdx.x;
    if (i < e) {
        int pos = atomicAdd(&cursor[dst[i]], 1);
        csr_src[pos] = src[i];
    }
}

// ---------------- fp32 tiled GEMM: C[M,N] = A[M,K] @ B[K,N] ----------------
// BM=BN=64, BK=16, 256 threads, 4x4 micro-tile per thread.

__global__ __launch_bounds__(256) void gemm_f32_kernel(const float* __restrict__ A,
                                                       const float* __restrict__ B,
                                                       float* __restrict__ C,
                                                       int M, int N, int K) {
    constexpr int BM = 64, BN = 64, BK = 16;
    __shared__ float As[BK][BM + 4];   // +4 pad keeps float4 alignment (68*4=272B)
    __shared__ float Bs[BK][BN + 4];
    const int tx = threadIdx.x & 15;
    const int ty = threadIdx.x >> 4;
    const int row0 = blockIdx.x * BM;
    const int col0 = blockIdx.y * BN;

    // A-tile load mapping: thread -> (kk = tid&15, base row = tid>>4)
    const int la_k = threadIdx.x & 15;
    const int la_r = threadIdx.x >> 4;
    // B-tile load mapping: thread -> (c = tid&63, kb = tid>>6)
    const int lb_c = threadIdx.x & 63;
    const int lb_k = threadIdx.x >> 6;

    float acc[4][4] = {};

    for (int k0 = 0; k0 < K; k0 += BK) {
#pragma unroll
        for (int rr = 0; rr < 4; ++rr) {
            int r  = la_r + rr * 16;
            int gr = row0 + r;
            As[la_k][r] = (gr < M) ? A[(size_t)gr * K + k0 + la_k] : 0.f;
        }
#pragma unroll
        for (int rr = 0; rr < 4; ++rr) {
            int kk = lb_k + rr * 4;
            Bs[kk][lb_c] = B[(size_t)(k0 + kk) * N + col0 + lb_c];
        }
        __syncthreads();
#pragma unroll
        for (int kk = 0; kk < BK; ++kk) {
            float4 av = *(const float4*)&As[kk][ty << 2];
            float4 bv = *(const float4*)&Bs[kk][tx << 2];
            float a[4] = {av.x, av.y, av.z, av.w};
            float b[4] = {bv.x, bv.y, bv.z, bv.w};
#pragma unroll
            for (int i = 0; i < 4; ++i)
#pragma unroll
                for (int j = 0; j < 4; ++j)
                    acc[i][j] = fmaf(a[i], b[j], acc[i][j]);
        }
        __syncthreads();
    }
#pragma unroll
    for (int i = 0; i < 4; ++i) {
        int r = row0 + (ty << 2) + i;
        if (r < M) {
            float4 o = make_float4(acc[i][0], acc[i][1], acc[i][2], acc[i][3]);
            *(float4*)&C[(size_t)r * N + col0 + (tx << 2)] = o;
        }
    }
}

// ---------------- attention scores ----------------
// layer 1: a_src[n,h] = sum_c h1[n,h,c]*att_src[h,c]  (one wave per node)

__global__ __launch_bounds__(256) void att1_kernel(const float* __restrict__ h1,
                                                   const float* __restrict__ w_s,
                                                   const float* __restrict__ w_d,
                                                   float* __restrict__ a_s,
                                                   float* __restrict__ a_d, int n_nodes) {
    int lane = threadIdx.x & 63;
    int n = blockIdx.x * 4 + (threadIdx.x >> 6);
    if (n >= n_nodes) return;
    const float* hp = h1 + (size_t)n * 256;
    float s[4], d[4];
#pragma unroll
    for (int hh = 0; hh < 4; ++hh) {
        float v = hp[hh * 64 + lane];
        s[hh] = v * w_s[hh * 64 + lane];
        d[hh] = v * w_d[hh * 64 + lane];
    }
#pragma unroll
    for (int off = 32; off > 0; off >>= 1) {
#pragma unroll
        for (int hh = 0; hh < 4; ++hh) {
            s[hh] += __shfl_xor(s[hh], off, 64);
            d[hh] += __shfl_xor(d[hh], off, 64);
        }
    }
    if (lane == 0) {
        *(float4*)(a_s + (size_t)n * 4) = make_float4(s[0], s[1], s[2], s[3]);
        *(float4*)(a_d + (size_t)n * 4) = make_float4(d[0], d[1], d[2], d[3]);
    }
}

__global__ __launch_bounds__(256) void att2_kernel(const float* __restrict__ h2,
                                                   const float* __restrict__ w_s,
                                                   const float* __restrict__ w_d,
                                                   float* __restrict__ a_s,
                                                   float* __restrict__ a_d, int n_nodes) {
    int lane = threadIdx.x & 63;
    int n = blockIdx.x * 4 + (threadIdx.x >> 6);
    if (n >= n_nodes) return;
    float v = h2[(size_t)n * 64 + lane];
    float s = v * w_s[lane];
    float d = v * w_d[lane];
#pragma unroll
    for (int off = 32; off > 0; off >>= 1) {
        s += __shfl_xor(s, off, 64);
        d += __shfl_xor(d, off, 64);
    }
    if (lane == 0) { a_s[n] = s; a_d[n] = d; }
}

// ---------------- aggregation (one wave per dst node) ----------------

__global__ __launch_bounds__(256) void agg1_kernel(const float* __restrict__ h1,
                                                   const float* __restrict__ a_s,
                                                   const float* __restrict__ a_d,
                                                   const int* __restrict__ row_ptr,
                                                   const int* __restrict__ csr_src,
                                                   const float* __restrict__ b1,
                                                   float* __restrict__ hout, int n_nodes) {
    int lane = threadIdx.x & 63;
    int n = blockIdx.x * 4 + (threadIdx.x >> 6);
    if (n >= n_nodes) return;
    const float4 ad = *(const float4*)(a_d + (size_t)n * 4);
    float acc0, acc1, acc2, acc3, ws0, ws1, ws2, ws3;
    {   // self loop
        const float4 as = *(const float4*)(a_s + (size_t)n * 4);
        float w0 = __expf(lrelu(as.x + ad.x));
        float w1 = __expf(lrelu(as.y + ad.y));
        float w2 = __expf(lrelu(as.z + ad.z));
        float w3 = __expf(lrelu(as.w + ad.w));
        const float* hp = h1 + (size_t)n * 256;
        acc0 = w0 * hp[lane];       acc1 = w1 * hp[64 + lane];
        acc2 = w2 * hp[128 + lane]; acc3 = w3 * hp[192 + lane];
        ws0 = w0; ws1 = w1; ws2 = w2; ws3 = w3;
    }
    int beg = row_ptr[n], end = row_ptr[n + 1];
    for (int e = beg; e < end; ++e) {
        int s = csr_src[e];
        const float4 as = *(const float4*)(a_s + (size_t)s * 4);
        float w0 = __expf(lrelu(as.x + ad.x));
        float w1 = __expf(lrelu(as.y + ad.y));
        float w2 = __expf(lrelu(as.z + ad.z));
        float w3 = __expf(lrelu(as.w + ad.w));
        const float* hp = h1 + (size_t)s * 256;
        acc0 = fmaf(w0, hp[lane], acc0);       acc1 = fmaf(w1, hp[64 + lane], acc1);
        acc2 = fmaf(w2, hp[128 + lane], acc2); acc3 = fmaf(w3, hp[192 + lane], acc3);
        ws0 += w0; ws1 += w1; ws2 += w2; ws3 += w3;
    }
    size_t o = (size_t)n * 256;
    hout[o + lane]       = elu1(acc0 / ws0 + b1[lane]);
    hout[o + 64 + lane]  = elu1(acc1 / ws1 + b1[64 + lane]);
    hout[o + 128 + lane] = elu1(acc2 / ws2 + b1[128 + lane]);
    hout[o + 192 + lane] = elu1(acc3 / ws3 + b1[192 + lane]);
}

__global__ __launch_bounds__(256) void agg2_kernel(const float* __restrict__ h2,
                                                   const float* __restrict__ a_s,
                                                   const float* __restrict__ a_d,
                                                   const int* __restrict__ row_ptr,
                                                   const int* __restrict__ csr_src,
                                                   const float* __restrict__ b2,
                                                   float* __restrict__ out, int n_nodes) {
    int lane = threadIdx.x & 63;
    int n = blockIdx.x * 4 + (threadIdx.x >> 6);
    if (n >= n_nodes) return;
    float ad = a_d[n];
    float w = __expf(lrelu(a_s[n] + ad));
    float acc = w * h2[(size_t)n * 64 + lane];
    float ws = w;
    int beg = row_ptr[n], end = row_ptr[n + 1];
    for (int e = beg; e < end; ++e) {
        int s = csr_src[e];
        float we = __expf(lrelu(a_s[s] + ad));
        acc = fmaf(we, h2[(size_t)s * 64 + lane], acc);
        ws += we;
    }
    out[(size_t)n * 64 + lane] = acc / ws + b2[lane];
}

// ---------------- launch ----------------

extern "C" void kernel_launch(void* const* d_in, const int* in_sizes, int n_in,
                              void* d_out, int out_size, void* d_ws, size_t ws_size,
                              hipStream_t stream) {
    const float* x      = (const float*)d_in[0];
    const int*   ei     = (const int*)d_in[1];    // [2, NE] int32 (harness convention)
    const float* W1     = (const float*)d_in[2];
    const float* att_s1 = (const float*)d_in[3];
    const float* att_d1 = (const float*)d_in[4];
    const float* b1     = (const float*)d_in[5];
    const float* W2     = (const float*)d_in[6];
    const float* att_s2 = (const float*)d_in[7];
    const float* att_d2 = (const float*)d_in[8];
    const float* b2     = (const float*)d_in[9];
    float* out = (float*)d_out;

    char* ws = (char*)d_ws;
    float* h1     = (float*)(ws + OFF_H1);
    float* h      = (float*)(ws + OFF_H);
    float* h2     = h1;                       // overlay: h1 dead after agg1
    float* as1    = (float*)(ws + OFF_AS1);
    float* ad1    = (float*)(ws + OFF_AD1);
    float* as2    = (float*)(ws + OFF_AS2);
    float* ad2    = (float*)(ws + OFF_AD2);
    int* row_ptr  = (int*)(ws + OFF_ROW);
    int* cursor   = (int*)(ws + OFF_CUR);     // doubles as counts buffer
    int* csr_src  = (int*)(ws + OFF_CSR);

    const int* e_src = ei;
    const int* e_dst = ei + NE;

    const int gE = (NE + 255) / 256;
    const int gN = (NN + 255) / 256;
    const int gW = (NN + 3) / 4;              // 4 waves/block, 1 node/wave

    // CSR build (counts -> scan -> scatter)
    zero_int_kernel<<<gN, 256, 0, stream>>>(cursor, NN);
    hist_kernel<<<gE, 256, 0, stream>>>(e_dst, cursor, NE);
    scan_kernel<<<1, 1024, 0, stream>>>(cursor, row_ptr, NN);
    copy_int_kernel<<<gN, 256, 0, stream>>>(row_ptr, cursor, NN);
    fill_kernel<<<gE, 256, 0, stream>>>(e_src, e_dst, cursor, csr_src, NE);

    // layer 1
    gemm_f32_kernel<<<dim3((NN + 63) / 64, 4), 256, 0, stream>>>(x, W1, h1, NN, 256, 256);
    att1_kernel<<<gW, 256, 0, stream>>>(h1, att_s1, att_d1, as1, ad1, NN);
    agg1_kernel<<<gW, 256, 0, stream>>>(h1, as1, ad1, row_ptr, csr_src, b1, h, NN);

    // layer 2
    gemm_f32_kernel<<<dim3((NN + 63) / 64, 1), 256, 0, stream>>>(h, W2, h2, NN, 64, 256);
    att2_kernel<<<gW, 256, 0, stream>>>(h2, att_s2, att_d2, as2, ad2, NN);
    agg2_kernel<<<gW, 256, 0, stream>>>(h2, as2, ad2, row_ptr, csr_src, b2, out, NN);
}

// Round 4
// 266.007 us; speedup vs baseline: 1.3396x; 1.3396x over previous
//
#include <hip/hip_runtime.h>
#include <hip/hip_bf16.h>
#include <math.h>

// ---------------------------------------------------------------------------
// Two-layer GAT. bf16 storage + MFMA GEMMs, fp32 accumulation everywhere.
//   cast x,W1,W2 -> bf16 (W transposed to [N][K])
//   L1: h1b = xb@W1 (MFMA, bf16 out); att1; agg1 (bf16 gather) -> hb (bf16)
//   L2: h2b = hb@W2 (MFMA); att2; agg2 -> out (fp32)
// Softmax max-subtraction skipped (shift-invariant, |logits| ~ O(1)).
// dst-CSR rebuilt on device every call (deterministic work per call).
// ---------------------------------------------------------------------------

#define NN 30000
#define NE 480000

typedef __attribute__((ext_vector_type(8))) short bf16x8;
typedef __attribute__((ext_vector_type(4))) float f32x4;

static constexpr size_t au(size_t x) { return (x + 255) & ~(size_t)255; }

static constexpr size_t SZ_XB  = (size_t)NN * 256 * 2;
static constexpr size_t SZ_H1B = (size_t)NN * 256 * 2;
static constexpr size_t SZ_HB  = (size_t)NN * 256 * 2;
static constexpr size_t SZ_H2B = (size_t)NN * 64 * 2;
static constexpr size_t SZ_W1T = 256 * 256 * 2;
static constexpr size_t SZ_W2T = 64 * 256 * 2;
static constexpr size_t SZ_AS1 = (size_t)NN * 4 * 4;
static constexpr size_t SZ_AS2 = (size_t)NN * 4;
static constexpr size_t SZ_ROW = (size_t)(NN + 1) * 4;
static constexpr size_t SZ_CUR = (size_t)NN * 4;
static constexpr size_t SZ_CSR = (size_t)NE * 4;

static constexpr size_t OFF_XB  = 0;
static constexpr size_t OFF_H1B = OFF_XB  + au(SZ_XB);
static constexpr size_t OFF_HB  = OFF_H1B + au(SZ_H1B);
static constexpr size_t OFF_H2B = OFF_HB  + au(SZ_HB);
static constexpr size_t OFF_W1T = OFF_H2B + au(SZ_H2B);
static constexpr size_t OFF_W2T = OFF_W1T + au(SZ_W1T);
static constexpr size_t OFF_AS1 = OFF_W2T + au(SZ_W2T);
static constexpr size_t OFF_AD1 = OFF_AS1 + au(SZ_AS1);
static constexpr size_t OFF_AS2 = OFF_AD1 + au(SZ_AS1);
static constexpr size_t OFF_AD2 = OFF_AS2 + au(SZ_AS2);
static constexpr size_t OFF_ROW = OFF_AD2 + au(SZ_AS2);
static constexpr size_t OFF_CUR = OFF_ROW + au(SZ_ROW);
static constexpr size_t OFF_CSR = OFF_CUR + au(SZ_CUR);
// total ~53 MB of d_ws

__device__ __forceinline__ float lrelu(float x) { return x > 0.f ? x : 0.2f * x; }
__device__ __forceinline__ float elu1(float x)  { return x > 0.f ? x : expm1f(x); }

__device__ __forceinline__ float bf2f(ushort u) {
    union { unsigned i; float f; } v; v.i = ((unsigned)u) << 16; return v.f;
}
__device__ __forceinline__ ushort f2bf(float f) {   // round-to-nearest-even
    union { float f; unsigned i; } v; v.f = f;
    unsigned x = v.i;
    return (ushort)((x + 0x7FFFu + ((x >> 16) & 1u)) >> 16);
}

// ---------------- casts ----------------

__global__ __launch_bounds__(256) void cast4_kernel(const float* __restrict__ in,
                                                    ushort* __restrict__ out, int n4) {
    int i = blockIdx.x * 256 + threadIdx.x;
    if (i < n4) {
        float4 v = ((const float4*)in)[i];
        ushort4 o;
        o.x = f2bf(v.x); o.y = f2bf(v.y); o.z = f2bf(v.z); o.w = f2bf(v.w);
        ((ushort4*)out)[i] = o;
    }
}

// in [R][C] fp32 -> out [C][R] bf16
__global__ __launch_bounds__(256) void castT_kernel(const float* __restrict__ in,
                                                    ushort* __restrict__ out, int R, int C) {
    int i = blockIdx.x * 256 + threadIdx.x;
    if (i < R * C) {
        int r = i / C, c = i - r * C;
        out[(size_t)c * R + r] = f2bf(in[i]);
    }
}

// ---------------- CSR build ----------------

__global__ __launch_bounds__(256) void zero_int_kernel(int* __restrict__ p, int n) {
    int i = blockIdx.x * 256 + threadIdx.x;
    if (i < n) p[i] = 0;
}

__global__ __launch_bounds__(256) void copy_int_kernel(const int* __restrict__ a,
                                                       int* __restrict__ b, int n) {
    int i = blockIdx.x * 256 + threadIdx.x;
    if (i < n) b[i] = a[i];
}

__global__ __launch_bounds__(256) void hist_kernel(const int* __restrict__ dst,
                                                   int* __restrict__ counts, int e) {
    int i = blockIdx.x * 256 + threadIdx.x;
    if (i < e) atomicAdd(&counts[dst[i]], 1);
}

// single-block exclusive scan (wave-shuffle based), counts[0..n) -> row_ptr[0..n]
__global__ __launch_bounds__(1024) void scan_kernel(const int* __restrict__ counts,
                                                    int* __restrict__ row_ptr, int n) {
    __shared__ int wpre[16];
    __shared__ int s_carry;
    const int tid = threadIdx.x, lane = tid & 63, wid = tid >> 6;
    if (tid == 0) s_carry = 0;
    __syncthreads();
    for (int base = 0; base < n; base += 1024) {
        int i = base + tid;
        int v = (i < n) ? counts[i] : 0;
        int x = v;
#pragma unroll
        for (int off = 1; off < 64; off <<= 1) {
            int t = __shfl_up(x, off, 64);
            if (lane >= off) x += t;
        }
        if (lane == 63) wpre[wid] = x;
        __syncthreads();
        int carry = s_carry;
        int wacc = 0;
        for (int w = 0; w < wid; ++w) wacc += wpre[w];
        if (i < n) row_ptr[i] = carry + wacc + x - v;   // exclusive
        __syncthreads();
        if (tid == 1023) s_carry = carry + wacc + x;
        __syncthreads();
    }
    if (tid == 0) row_ptr[n] = s_carry;
}

__global__ __launch_bounds__(256) void fill_kernel(const int* __restrict__ src,
                                                   const int* __restrict__ dst,
                                                   int* __restrict__ cursor,
                                                   int* __restrict__ csr_src, int e) {
    int i = blockIdx.x * 256 + threadIdx.x;
    if (i < e) {
        int pos = atomicAdd(&cursor[dst[i]], 1);
        csr_src[pos] = src[i];
    }
}

// ---------------- bf16 MFMA GEMM: C[M,N] = A[M,K] @ BT[N,K]^T ----------------
// Register-only (no LDS): A/B fragments loaded straight from global; W is tiny
// and L2-resident, A rows are read ~WAVES_N times through L1/L2.
// Fragment layout (16x16x32 bf16, m89-verified): A row = lane&15,
// k = (lane>>4)*8+j contiguous; B col = lane&15 (from BT row), same k;
// C/D col = lane&15, row = (lane>>4)*4+reg.

template<int WM, int WN>
__global__ __launch_bounds__(WM * WN * 64)
void gemm_bf16_kernel(const ushort* __restrict__ A, const ushort* __restrict__ BT,
                      ushort* __restrict__ C, int M, int N, int K) {
    const int lane = threadIdx.x & 63;
    const int wid  = threadIdx.x >> 6;
    const int wm = wid / WN, wn = wid % WN;
    const int r  = lane & 15;
    const int kq = lane >> 4;                 // 8 k's per quarter-wave
    const long row0 = (long)blockIdx.x * (WM * 64) + wm * 64;
    const long col0 = (long)blockIdx.y * (WN * 64) + wn * 64;

    f32x4 acc[4][4] = {};
    const int nks = K >> 5;
    for (int ks = 0; ks < nks; ++ks) {
        const int kb = ks * 32 + kq * 8;
        bf16x8 bfr[4];
#pragma unroll
        for (int n = 0; n < 4; ++n)
            bfr[n] = *(const bf16x8*)(BT + (col0 + n * 16 + r) * (long)K + kb);
#pragma unroll
        for (int m = 0; m < 4; ++m) {
            long rr = row0 + m * 16 + r; if (rr >= M) rr = M - 1;   // clamp, store predicated
            bf16x8 afr = *(const bf16x8*)(A + rr * (long)K + kb);
#pragma unroll
            for (int n = 0; n < 4; ++n)
                acc[m][n] = __builtin_amdgcn_mfma_f32_16x16x32_bf16(afr, bfr[n], acc[m][n], 0, 0, 0);
        }
    }
#pragma unroll
    for (int m = 0; m < 4; ++m)
#pragma unroll
        for (int reg = 0; reg < 4; ++reg) {
            long rr = row0 + m * 16 + kq * 4 + reg;
            if (rr < M) {
                ushort* cp = C + rr * (long)N + col0 + r;
#pragma unroll
                for (int n = 0; n < 4; ++n)
                    cp[n * 16] = f2bf(acc[m][n][reg]);
            }
        }
}

// ---------------- attention scores (bf16 h) ----------------

__global__ __launch_bounds__(256) void att1_kernel(const ushort* __restrict__ h1b,
                                                   const float* __restrict__ w_s,
                                                   const float* __restrict__ w_d,
                                                   float* __restrict__ a_s,
                                                   float* __restrict__ a_d, int n_nodes) {
    int lane = threadIdx.x & 63;
    int n = blockIdx.x * 4 + (threadIdx.x >> 6);
    if (n >= n_nodes) return;
    const ushort* hp = h1b + (size_t)n * 256;
    float s[4], d[4];
#pragma unroll
    for (int hh = 0; hh < 4; ++hh) {
        float v = bf2f(hp[hh * 64 + lane]);
        s[hh] = v * w_s[hh * 64 + lane];
        d[hh] = v * w_d[hh * 64 + lane];
    }
#pragma unroll
    for (int off = 32; off > 0; off >>= 1) {
#pragma unroll
        for (int hh = 0; hh < 4; ++hh) {
            s[hh] += __shfl_xor(s[hh], off, 64);
            d[hh] += __shfl_xor(d[hh], off, 64);
        }
    }
    if (lane == 0) {
        *(float4*)(a_s + (size_t)n * 4) = make_float4(s[0], s[1], s[2], s[3]);
        *(float4*)(a_d + (size_t)n * 4) = make_float4(d[0], d[1], d[2], d[3]);
    }
}

__global__ __launch_bounds__(256) void att2_kernel(const ushort* __restrict__ h2b,
                                                   const float* __restrict__ w_s,
                                                   const float* __restrict__ w_d,
                                                   float* __restrict__ a_s,
                                                   float* __restrict__ a_d, int n_nodes) {
    int lane = threadIdx.x & 63;
    int n = blockIdx.x * 4 + (threadIdx.x >> 6);
    if (n >= n_nodes) return;
    float v = bf2f(h2b[(size_t)n * 64 + lane]);
    float s = v * w_s[lane];
    float d = v * w_d[lane];
#pragma unroll
    for (int off = 32; off > 0; off >>= 1) {
        s += __shfl_xor(s, off, 64);
        d += __shfl_xor(d, off, 64);
    }
    if (lane == 0) { a_s[n] = s; a_d[n] = d; }
}

// ---------------- aggregation (one wave per dst node) ----------------
// Lane l owns channels 4l..4l+3 (all in head l>>4). Per-edge payload: 512 B
// bf16 row (ushort4/lane, coalesced) + one broadcast a_s scalar.

__global__ __launch_bounds__(256) void agg1_kernel(const ushort* __restrict__ h1b,
                                                   const float* __restrict__ a_s,
                                                   const float* __restrict__ a_d,
                                                   const int* __restrict__ row_ptr,
                                                   const int* __restrict__ csr_src,
                                                   const float* __restrict__ b1,
                                                   ushort* __restrict__ hb, int n_nodes) {
    const int lane = threadIdx.x & 63;
    const int n = blockIdx.x * 4 + (threadIdx.x >> 6);
    if (n >= n_nodes) return;
    const int head = lane >> 4;
    const float ad = a_d[(size_t)n * 4 + head];
    float acc0, acc1, acc2, acc3, ws;
    {   // self loop
        float w = __expf(lrelu(a_s[(size_t)n * 4 + head] + ad));
        ushort4 hv = *(const ushort4*)(h1b + (size_t)n * 256 + 4 * lane);
        acc0 = w * bf2f(hv.x); acc1 = w * bf2f(hv.y);
        acc2 = w * bf2f(hv.z); acc3 = w * bf2f(hv.w);
        ws = w;
    }
    int beg = row_ptr[n], end = row_ptr[n + 1];
    for (int e = beg; e < end; ++e) {
        int s = csr_src[e];
        float w = __expf(lrelu(a_s[(size_t)s * 4 + head] + ad));
        ushort4 hv = *(const ushort4*)(h1b + (size_t)s * 256 + 4 * lane);
        acc0 = fmaf(w, bf2f(hv.x), acc0);
        acc1 = fmaf(w, bf2f(hv.y), acc1);
        acc2 = fmaf(w, bf2f(hv.z), acc2);
        acc3 = fmaf(w, bf2f(hv.w), acc3);
        ws += w;
    }
    float4 bv = *(const float4*)(b1 + 4 * lane);
    ushort4 o;
    o.x = f2bf(elu1(acc0 / ws + bv.x));
    o.y = f2bf(elu1(acc1 / ws + bv.y));
    o.z = f2bf(elu1(acc2 / ws + bv.z));
    o.w = f2bf(elu1(acc3 / ws + bv.w));
    *(ushort4*)(hb + (size_t)n * 256 + 4 * lane) = o;
}

__global__ __launch_bounds__(256) void agg2_kernel(const ushort* __restrict__ h2b,
                                                   const float* __restrict__ a_s,
                                                   const float* __restrict__ a_d,
                                                   const int* __restrict__ row_ptr,
                                                   const int* __restrict__ csr_src,
                                                   const float* __restrict__ b2,
                                                   float* __restrict__ out, int n_nodes) {
    const int lane = threadIdx.x & 63;
    const int n = blockIdx.x * 4 + (threadIdx.x >> 6);
    if (n >= n_nodes) return;
    const float ad = a_d[n];
    float w = __expf(lrelu(a_s[n] + ad));
    float acc = w * bf2f(h2b[(size_t)n * 64 + lane]);
    float ws = w;
    int beg = row_ptr[n], end = row_ptr[n + 1];
    for (int e = beg; e < end; ++e) {
        int s = csr_src[e];
        float we = __expf(lrelu(a_s[s] + ad));
        acc = fmaf(we, bf2f(h2b[(size_t)s * 64 + lane]), acc);
        ws += we;
    }
    out[(size_t)n * 64 + lane] = acc / ws + b2[lane];
}

// ---------------- launch ----------------

extern "C" void kernel_launch(void* const* d_in, const int* in_sizes, int n_in,
                              void* d_out, int out_size, void* d_ws, size_t ws_size,
                              hipStream_t stream) {
    const float* x      = (const float*)d_in[0];
    const int*   ei     = (const int*)d_in[1];    // [2, NE] int32
    const float* W1     = (const float*)d_in[2];
    const float* att_s1 = (const float*)d_in[3];
    const float* att_d1 = (const float*)d_in[4];
    const float* b1     = (const float*)d_in[5];
    const float* W2     = (const float*)d_in[6];
    const float* att_s2 = (const float*)d_in[7];
    const float* att_d2 = (const float*)d_in[8];
    const float* b2     = (const float*)d_in[9];
    float* out = (float*)d_out;

    char* ws = (char*)d_ws;
    ushort* xb    = (ushort*)(ws + OFF_XB);
    ushort* h1b   = (ushort*)(ws + OFF_H1B);
    ushort* hb    = (ushort*)(ws + OFF_HB);
    ushort* h2b   = (ushort*)(ws + OFF_H2B);
    ushort* w1t   = (ushort*)(ws + OFF_W1T);
    ushort* w2t   = (ushort*)(ws + OFF_W2T);
    float* as1    = (float*)(ws + OFF_AS1);
    float* ad1    = (float*)(ws + OFF_AD1);
    float* as2    = (float*)(ws + OFF_AS2);
    float* ad2    = (float*)(ws + OFF_AD2);
    int* row_ptr  = (int*)(ws + OFF_ROW);
    int* cursor   = (int*)(ws + OFF_CUR);
    int* csr_src  = (int*)(ws + OFF_CSR);

    const int* e_src = ei;
    const int* e_dst = ei + NE;

    const int gE = (NE + 255) / 256;
    const int gN = (NN + 255) / 256;
    const int gW = (NN + 3) / 4;              // 4 waves/block, 1 node/wave
    const int nX4 = NN * 256 / 4;

    // CSR build (counts -> scan -> scatter)
    zero_int_kernel<<<gN, 256, 0, stream>>>(cursor, NN);
    hist_kernel<<<gE, 256, 0, stream>>>(e_dst, cursor, NE);
    scan_kernel<<<1, 1024, 0, stream>>>(cursor, row_ptr, NN);
    copy_int_kernel<<<gN, 256, 0, stream>>>(row_ptr, cursor, NN);
    fill_kernel<<<gE, 256, 0, stream>>>(e_src, e_dst, cursor, csr_src, NE);

    // casts
    cast4_kernel<<<(nX4 + 255) / 256, 256, 0, stream>>>(x, xb, nX4);
    castT_kernel<<<(256 * 256 + 255) / 256, 256, 0, stream>>>(W1, w1t, 256, 256);
    castT_kernel<<<(256 * 64 + 255) / 256, 256, 0, stream>>>(W2, w2t, 256, 64);

    // layer 1
    gemm_bf16_kernel<2, 2><<<dim3((NN + 127) / 128, 2), 256, 0, stream>>>(xb, w1t, h1b, NN, 256, 256);
    att1_kernel<<<gW, 256, 0, stream>>>(h1b, att_s1, att_d1, as1, ad1, NN);
    agg1_kernel<<<gW, 256, 0, stream>>>(h1b, as1, ad1, row_ptr, csr_src, b1, hb, NN);

    // layer 2
    gemm_bf16_kernel<4, 1><<<dim3((NN + 255) / 256, 1), 256, 0, stream>>>(hb, w2t, h2b, NN, 64, 256);
    att2_kernel<<<gW, 256, 0, stream>>>(h2b, att_s2, att_d2, as2, ad2, NN);
    agg2_kernel<<<gW, 256, 0, stream>>>(h2b, as2, ad2, row_ptr, csr_src, b2, out, NN);
}

// Round 5
// 202.133 us; speedup vs baseline: 1.7629x; 1.3160x over previous
//
#include <hip/hip_runtime.h>
#include <hip/hip_bf16.h>
#include <math.h>

// ---------------------------------------------------------------------------
// Two-layer GAT. bf16 storage + MFMA GEMMs (fp32 accum), attention scores
// fused into GEMM epilogues, CSR gather aggregation with 4x unrolled edge loop.
// Pipeline (9 dispatches):
//   memset(cursor) -> hist -> scan(row_ptr+cursor) -> fill       (CSR by dst)
//   cast4(x->xb) ; castW(W1,W2 -> transposed bf16)
//   gemm_att1 (h1b + a_s1/a_d1) -> agg1 -> hb
//   gemm_att2 (h2b + a_s2/a_d2) -> agg2 -> out
// Softmax max-subtraction skipped (shift-invariant, |logits| ~ O(1)).
// ---------------------------------------------------------------------------

#define NN 30000
#define NE 480000

typedef __attribute__((ext_vector_type(8))) short bf16x8;
typedef __attribute__((ext_vector_type(4))) float f32x4;

static constexpr size_t au(size_t x) { return (x + 255) & ~(size_t)255; }

static constexpr size_t SZ_XB  = (size_t)NN * 256 * 2;
static constexpr size_t SZ_H1B = (size_t)NN * 256 * 2;
static constexpr size_t SZ_HB  = (size_t)NN * 256 * 2;
static constexpr size_t SZ_H2B = (size_t)NN * 64 * 2;
static constexpr size_t SZ_W1T = 256 * 256 * 2;
static constexpr size_t SZ_W2T = 64 * 256 * 2;
static constexpr size_t SZ_AS1 = (size_t)NN * 4 * 4;
static constexpr size_t SZ_AS2 = (size_t)NN * 4;
static constexpr size_t SZ_ROW = (size_t)(NN + 1) * 4;
static constexpr size_t SZ_CUR = (size_t)NN * 4;
static constexpr size_t SZ_CSR = (size_t)NE * 4;

static constexpr size_t OFF_XB  = 0;
static constexpr size_t OFF_H1B = OFF_XB  + au(SZ_XB);
static constexpr size_t OFF_HB  = OFF_H1B + au(SZ_H1B);
static constexpr size_t OFF_H2B = OFF_HB  + au(SZ_HB);
static constexpr size_t OFF_W1T = OFF_H2B + au(SZ_H2B);
static constexpr size_t OFF_W2T = OFF_W1T + au(SZ_W1T);
static constexpr size_t OFF_AS1 = OFF_W2T + au(SZ_W2T);
static constexpr size_t OFF_AD1 = OFF_AS1 + au(SZ_AS1);
static constexpr size_t OFF_AS2 = OFF_AD1 + au(SZ_AS1);
static constexpr size_t OFF_AD2 = OFF_AS2 + au(SZ_AS2);
static constexpr size_t OFF_ROW = OFF_AD2 + au(SZ_AS2);
static constexpr size_t OFF_CUR = OFF_ROW + au(SZ_ROW);
static constexpr size_t OFF_CSR = OFF_CUR + au(SZ_CUR);

__device__ __forceinline__ float lrelu(float x) { return x > 0.f ? x : 0.2f * x; }
__device__ __forceinline__ float elu1(float x)  { return x > 0.f ? x : expm1f(x); }

__device__ __forceinline__ float bf2f(ushort u) {
    union { unsigned i; float f; } v; v.i = ((unsigned)u) << 16; return v.f;
}
__device__ __forceinline__ ushort f2bf(float f) {   // round-to-nearest-even
    union { float f; unsigned i; } v; v.f = f;
    unsigned x = v.i;
    return (ushort)((x + 0x7FFFu + ((x >> 16) & 1u)) >> 16);
}

// ---------------- casts ----------------

__global__ __launch_bounds__(256) void cast4_kernel(const float* __restrict__ in,
                                                    ushort* __restrict__ out, int n4) {
    int i = blockIdx.x * 256 + threadIdx.x;
    if (i < n4) {
        float4 v = ((const float4*)in)[i];
        ushort4 o;
        o.x = f2bf(v.x); o.y = f2bf(v.y); o.z = f2bf(v.z); o.w = f2bf(v.w);
        ((ushort4*)out)[i] = o;
    }
}

// W1 [256][256] -> w1t [256][256]^T ; W2 [256][64] -> w2t [64][256]^T, one launch
__global__ __launch_bounds__(256) void castW_kernel(const float* __restrict__ W1,
                                                    const float* __restrict__ W2,
                                                    ushort* __restrict__ w1t,
                                                    ushort* __restrict__ w2t) {
    int i = blockIdx.x * 256 + threadIdx.x;
    if (i < 256 * 256) {
        int r = i >> 8, c = i & 255;
        w1t[c * 256 + r] = f2bf(W1[i]);
    } else {
        int j = i - 256 * 256;
        if (j < 256 * 64) {
            int r = j >> 6, c = j & 63;
            w2t[c * 256 + r] = f2bf(W2[j]);
        }
    }
}

// ---------------- CSR build ----------------

__global__ __launch_bounds__(256) void hist_kernel(const int* __restrict__ dst,
                                                   int* __restrict__ counts, int e) {
    int i = blockIdx.x * 256 + threadIdx.x;
    if (i < e) atomicAdd(&counts[dst[i]], 1);
}

// single-block single-pass exclusive scan: counts -> row_ptr[0..n] and cursor copy.
// 1024 threads x 30 serial elements covers n=30000.
__global__ __launch_bounds__(1024) void scan_kernel(const int* __restrict__ counts,
                                                    int* __restrict__ row_ptr,
                                                    int* __restrict__ cursor, int n) {
    constexpr int CH = 30;
    __shared__ int wsum[16];
    const int tid = threadIdx.x, lane = tid & 63, wid = tid >> 6;
    const int base = tid * CH;
    int v[CH];
    int tot = 0;
#pragma unroll
    for (int j = 0; j < CH; ++j) {
        int i = base + j;
        v[j] = (i < n) ? counts[i] : 0;
        tot += v[j];
    }
    int x = tot;
#pragma unroll
    for (int off = 1; off < 64; off <<= 1) {
        int t = __shfl_up(x, off, 64);
        if (lane >= off) x += t;
    }
    if (lane == 63) wsum[wid] = x;
    __syncthreads();
    int wbase = 0;
    for (int w = 0; w < wid; ++w) wbase += wsum[w];
    int run = wbase + x - tot;               // exclusive prefix for this thread
#pragma unroll
    for (int j = 0; j < CH; ++j) {
        int i = base + j;
        if (i < n) { row_ptr[i] = run; cursor[i] = run; }
        run += v[j];
    }
    if (tid == 1023) row_ptr[n] = run;       // total (this thread's range is all OOB)
}

__global__ __launch_bounds__(256) void fill_kernel(const int* __restrict__ src,
                                                   const int* __restrict__ dst,
                                                   int* __restrict__ cursor,
                                                   int* __restrict__ csr_src, int e) {
    int i = blockIdx.x * 256 + threadIdx.x;
    if (i < e) {
        int pos = atomicAdd(&cursor[dst[i]], 1);
        csr_src[pos] = src[i];
    }
}

// ---------------- GEMM1 + fused att1 ----------------
// C[M,256] = A[M,256] @ BT[256,256]^T, 512 threads (8 waves: wm 0..1 x wn 0..3),
// block tile 128x256. Epilogue computes a_s/a_d = h . att (fp32 acc, in-wave
// shfl reduce over 16 cols + LDS combine across n-strips; strip == head).
// Fragment layout (verified): A row=lane&15, k=(lane>>4)*8+j; C/D col=lane&15,
// row=(lane>>4)*4+reg.

__global__ __launch_bounds__(512)
void gemm_att1_kernel(const ushort* __restrict__ A, const ushort* __restrict__ BT,
                      const float* __restrict__ att_s, const float* __restrict__ att_d,
                      ushort* __restrict__ C, float* __restrict__ a_s,
                      float* __restrict__ a_d, int M) {
    constexpr int K = 256, N = 256;
    __shared__ float s_s[128 * 4], s_d[128 * 4];
    const int lane = threadIdx.x & 63;
    const int wid  = threadIdx.x >> 6;
    const int wm = wid >> 2, wn = wid & 3;
    const int r  = lane & 15;
    const int kq = lane >> 4;
    const long row0  = (long)blockIdx.x * 128;
    const long rbase = row0 + wm * 64;
    const int  col0  = wn * 64;

    f32x4 acc[4][4] = {};
#pragma unroll 2
    for (int ks = 0; ks < K / 32; ++ks) {
        const int kb = ks * 32 + kq * 8;
        bf16x8 bfr[4];
#pragma unroll
        for (int n = 0; n < 4; ++n)
            bfr[n] = *(const bf16x8*)(BT + (long)(col0 + n * 16 + r) * K + kb);
#pragma unroll
        for (int m = 0; m < 4; ++m) {
            long rr = rbase + m * 16 + r; if (rr >= M) rr = M - 1;
            bf16x8 afr = *(const bf16x8*)(A + rr * (long)K + kb);
#pragma unroll
            for (int n = 0; n < 4; ++n)
                acc[m][n] = __builtin_amdgcn_mfma_f32_16x16x32_bf16(afr, bfr[n], acc[m][n], 0, 0, 0);
        }
    }
    // C (h1b) store
#pragma unroll
    for (int m = 0; m < 4; ++m)
#pragma unroll
        for (int reg = 0; reg < 4; ++reg) {
            long rr = rbase + m * 16 + kq * 4 + reg;
            if (rr < M) {
                ushort* cp = C + rr * (long)N + col0 + r;
#pragma unroll
                for (int n = 0; n < 4; ++n) cp[n * 16] = f2bf(acc[m][n][reg]);
            }
        }
    // fused attention scores (head == wn)
    float aws[4], awd[4];
#pragma unroll
    for (int n = 0; n < 4; ++n) {
        aws[n] = att_s[col0 + n * 16 + r];
        awd[n] = att_d[col0 + n * 16 + r];
    }
#pragma unroll
    for (int m = 0; m < 4; ++m)
#pragma unroll
        for (int reg = 0; reg < 4; ++reg) {
            float ps = acc[m][0][reg] * aws[0] + acc[m][1][reg] * aws[1]
                     + acc[m][2][reg] * aws[2] + acc[m][3][reg] * aws[3];
            float pd = acc[m][0][reg] * awd[0] + acc[m][1][reg] * awd[1]
                     + acc[m][2][reg] * awd[2] + acc[m][3][reg] * awd[3];
#pragma unroll
            for (int off = 1; off < 16; off <<= 1) {
                ps += __shfl_xor(ps, off, 64);
                pd += __shfl_xor(pd, off, 64);
            }
            if (r == 0) {
                int rl = wm * 64 + m * 16 + kq * 4 + reg;
                s_s[rl * 4 + wn] = ps;
                s_d[rl * 4 + wn] = pd;
            }
        }
    __syncthreads();
    int t = threadIdx.x;                     // 512 = 128 rows x 4 heads
    long row = row0 + (t >> 2);
    if (row < M) {
        a_s[row * 4 + (t & 3)] = s_s[t];
        a_d[row * 4 + (t & 3)] = s_d[t];
    }
}

// ---------------- GEMM2 + fused att2 ----------------
// C[M,64] = A[M,256] @ BT[64,256]^T, 256 threads (4 waves: wm 0..3), tile 256x64.
// One wave spans all 64 cols -> att reduce is purely in-wave.

__global__ __launch_bounds__(256)
void gemm_att2_kernel(const ushort* __restrict__ A, const ushort* __restrict__ BT,
                      const float* __restrict__ att_s, const float* __restrict__ att_d,
                      ushort* __restrict__ C, float* __restrict__ a_s,
                      float* __restrict__ a_d, int M) {
    constexpr int K = 256, N = 64;
    const int lane = threadIdx.x & 63;
    const int wm   = threadIdx.x >> 6;
    const int r  = lane & 15;
    const int kq = lane >> 4;
    const long rbase = (long)blockIdx.x * 256 + wm * 64;

    f32x4 acc[4][4] = {};
#pragma unroll 2
    for (int ks = 0; ks < K / 32; ++ks) {
        const int kb = ks * 32 + kq * 8;
        bf16x8 bfr[4];
#pragma unroll
        for (int n = 0; n < 4; ++n)
            bfr[n] = *(const bf16x8*)(BT + (long)(n * 16 + r) * K + kb);
#pragma unroll
        for (int m = 0; m < 4; ++m) {
            long rr = rbase + m * 16 + r; if (rr >= M) rr = M - 1;
            bf16x8 afr = *(const bf16x8*)(A + rr * (long)K + kb);
#pragma unroll
            for (int n = 0; n < 4; ++n)
                acc[m][n] = __builtin_amdgcn_mfma_f32_16x16x32_bf16(afr, bfr[n], acc[m][n], 0, 0, 0);
        }
    }
#pragma unroll
    for (int m = 0; m < 4; ++m)
#pragma unroll
        for (int reg = 0; reg < 4; ++reg) {
            long rr = rbase + m * 16 + kq * 4 + reg;
            if (rr < M) {
                ushort* cp = C + rr * (long)N + r;
#pragma unroll
                for (int n = 0; n < 4; ++n) cp[n * 16] = f2bf(acc[m][n][reg]);
            }
        }
    float aws[4], awd[4];
#pragma unroll
    for (int n = 0; n < 4; ++n) {
        aws[n] = att_s[n * 16 + r];
        awd[n] = att_d[n * 16 + r];
    }
#pragma unroll
    for (int m = 0; m < 4; ++m)
#pragma unroll
        for (int reg = 0; reg < 4; ++reg) {
            float ps = acc[m][0][reg] * aws[0] + acc[m][1][reg] * aws[1]
                     + acc[m][2][reg] * aws[2] + acc[m][3][reg] * aws[3];
            float pd = acc[m][0][reg] * awd[0] + acc[m][1][reg] * awd[1]
                     + acc[m][2][reg] * awd[2] + acc[m][3][reg] * awd[3];
#pragma unroll
            for (int off = 1; off < 16; off <<= 1) {
                ps += __shfl_xor(ps, off, 64);
                pd += __shfl_xor(pd, off, 64);
            }
            if (r == 0) {
                long row = rbase + m * 16 + kq * 4 + reg;
                if (row < M) { a_s[row] = ps; a_d[row] = pd; }
            }
        }
}

// ---------------- aggregation (one wave per dst node, 4x unrolled) ----------

__global__ __launch_bounds__(256) void agg1_kernel(const ushort* __restrict__ h1b,
                                                   const float* __restrict__ a_s,
                                                   const float* __restrict__ a_d,
                                                   const int* __restrict__ row_ptr,
                                                   const int* __restrict__ csr_src,
                                                   const float* __restrict__ b1,
                                                   ushort* __restrict__ hb, int n_nodes) {
    const int lane = threadIdx.x & 63;
    const int n = blockIdx.x * 4 + (threadIdx.x >> 6);
    if (n >= n_nodes) return;
    const int head = lane >> 4;
    const float ad = a_d[(size_t)n * 4 + head];
    float acc0, acc1, acc2, acc3, ws;
    {   // self loop
        float w = __expf(lrelu(a_s[(size_t)n * 4 + head] + ad));
        ushort4 hv = *(const ushort4*)(h1b + (size_t)n * 256 + 4 * lane);
        acc0 = w * bf2f(hv.x); acc1 = w * bf2f(hv.y);
        acc2 = w * bf2f(hv.z); acc3 = w * bf2f(hv.w);
        ws = w;
    }
    int e = row_ptr[n];
    const int end = row_ptr[n + 1];
    for (; e + 4 <= end; e += 4) {
        int s0 = csr_src[e],     s1 = csr_src[e + 1];
        int s2 = csr_src[e + 2], s3 = csr_src[e + 3];
        float q0 = a_s[(size_t)s0 * 4 + head], q1 = a_s[(size_t)s1 * 4 + head];
        float q2 = a_s[(size_t)s2 * 4 + head], q3 = a_s[(size_t)s3 * 4 + head];
        ushort4 h0 = *(const ushort4*)(h1b + (size_t)s0 * 256 + 4 * lane);
        ushort4 h1 = *(const ushort4*)(h1b + (size_t)s1 * 256 + 4 * lane);
        ushort4 h2 = *(const ushort4*)(h1b + (size_t)s2 * 256 + 4 * lane);
        ushort4 h3 = *(const ushort4*)(h1b + (size_t)s3 * 256 + 4 * lane);
        float w0 = __expf(lrelu(q0 + ad)), w1 = __expf(lrelu(q1 + ad));
        float w2 = __expf(lrelu(q2 + ad)), w3 = __expf(lrelu(q3 + ad));
        acc0 = fmaf(w0, bf2f(h0.x), acc0); acc1 = fmaf(w0, bf2f(h0.y), acc1);
        acc2 = fmaf(w0, bf2f(h0.z), acc2); acc3 = fmaf(w0, bf2f(h0.w), acc3);
        acc0 = fmaf(w1, bf2f(h1.x), acc0); acc1 = fmaf(w1, bf2f(h1.y), acc1);
        acc2 = fmaf(w1, bf2f(h1.z), acc2); acc3 = fmaf(w1, bf2f(h1.w), acc3);
        acc0 = fmaf(w2, bf2f(h2.x), acc0); acc1 = fmaf(w2, bf2f(h2.y), acc1);
        acc2 = fmaf(w2, bf2f(h2.z), acc2); acc3 = fmaf(w2, bf2f(h2.w), acc3);
        acc0 = fmaf(w3, bf2f(h3.x), acc0); acc1 = fmaf(w3, bf2f(h3.y), acc1);
        acc2 = fmaf(w3, bf2f(h3.z), acc2); acc3 = fmaf(w3, bf2f(h3.w), acc3);
        ws += (w0 + w1) + (w2 + w3);
    }
    for (; e < end; ++e) {
        int s = csr_src[e];
        float w = __expf(lrelu(a_s[(size_t)s * 4 + head] + ad));
        ushort4 hv = *(const ushort4*)(h1b + (size_t)s * 256 + 4 * lane);
        acc0 = fmaf(w, bf2f(hv.x), acc0); acc1 = fmaf(w, bf2f(hv.y), acc1);
        acc2 = fmaf(w, bf2f(hv.z), acc2); acc3 = fmaf(w, bf2f(hv.w), acc3);
        ws += w;
    }
    float4 bv = *(const float4*)(b1 + 4 * lane);
    float inv = 1.f / ws;
    ushort4 o;
    o.x = f2bf(elu1(acc0 * inv + bv.x));
    o.y = f2bf(elu1(acc1 * inv + bv.y));
    o.z = f2bf(elu1(acc2 * inv + bv.z));
    o.w = f2bf(elu1(acc3 * inv + bv.w));
    *(ushort4*)(hb + (size_t)n * 256 + 4 * lane) = o;
}

__global__ __launch_bounds__(256) void agg2_kernel(const ushort* __restrict__ h2b,
                                                   const float* __restrict__ a_s,
                                                   const float* __restrict__ a_d,
                                                   const int* __restrict__ row_ptr,
                                                   const int* __restrict__ csr_src,
                                                   const float* __restrict__ b2,
                                                   float* __restrict__ out, int n_nodes) {
    const int lane = threadIdx.x & 63;
    const int n = blockIdx.x * 4 + (threadIdx.x >> 6);
    if (n >= n_nodes) return;
    const float ad = a_d[n];
    float w = __expf(lrelu(a_s[n] + ad));
    float acc = w * bf2f(h2b[(size_t)n * 64 + lane]);
    float ws = w;
    int e = row_ptr[n];
    const int end = row_ptr[n + 1];
    for (; e + 4 <= end; e += 4) {
        int s0 = csr_src[e],     s1 = csr_src[e + 1];
        int s2 = csr_src[e + 2], s3 = csr_src[e + 3];
        float q0 = a_s[s0], q1 = a_s[s1], q2 = a_s[s2], q3 = a_s[s3];
        ushort v0 = h2b[(size_t)s0 * 64 + lane];
        ushort v1 = h2b[(size_t)s1 * 64 + lane];
        ushort v2 = h2b[(size_t)s2 * 64 + lane];
        ushort v3 = h2b[(size_t)s3 * 64 + lane];
        float w0 = __expf(lrelu(q0 + ad)), w1 = __expf(lrelu(q1 + ad));
        float w2 = __expf(lrelu(q2 + ad)), w3 = __expf(lrelu(q3 + ad));
        acc = fmaf(w0, bf2f(v0), acc);
        acc = fmaf(w1, bf2f(v1), acc);
        acc = fmaf(w2, bf2f(v2), acc);
        acc = fmaf(w3, bf2f(v3), acc);
        ws += (w0 + w1) + (w2 + w3);
    }
    for (; e < end; ++e) {
        int s = csr_src[e];
        float we = __expf(lrelu(a_s[s] + ad));
        acc = fmaf(we, bf2f(h2b[(size_t)s * 64 + lane]), acc);
        ws += we;
    }
    out[(size_t)n * 64 + lane] = acc / ws + b2[lane];
}

// ---------------- launch ----------------

extern "C" void kernel_launch(void* const* d_in, const int* in_sizes, int n_in,
                              void* d_out, int out_size, void* d_ws, size_t ws_size,
                              hipStream_t stream) {
    const float* x      = (const float*)d_in[0];
    const int*   ei     = (const int*)d_in[1];    // [2, NE] int32
    const float* W1     = (const float*)d_in[2];
    const float* att_s1 = (const float*)d_in[3];
    const float* att_d1 = (const float*)d_in[4];
    const float* b1     = (const float*)d_in[5];
    const float* W2     = (const float*)d_in[6];
    const float* att_s2 = (const float*)d_in[7];
    const float* att_d2 = (const float*)d_in[8];
    const float* b2     = (const float*)d_in[9];
    float* out = (float*)d_out;

    char* ws = (char*)d_ws;
    ushort* xb    = (ushort*)(ws + OFF_XB);
    ushort* h1b   = (ushort*)(ws + OFF_H1B);
    ushort* hb    = (ushort*)(ws + OFF_HB);
    ushort* h2b   = (ushort*)(ws + OFF_H2B);
    ushort* w1t   = (ushort*)(ws + OFF_W1T);
    ushort* w2t   = (ushort*)(ws + OFF_W2T);
    float* as1    = (float*)(ws + OFF_AS1);
    float* ad1    = (float*)(ws + OFF_AD1);
    float* as2    = (float*)(ws + OFF_AS2);
    float* ad2    = (float*)(ws + OFF_AD2);
    int* row_ptr  = (int*)(ws + OFF_ROW);
    int* cursor   = (int*)(ws + OFF_CUR);
    int* csr_src  = (int*)(ws + OFF_CSR);

    const int* e_src = ei;
    const int* e_dst = ei + NE;

    const int gE = (NE + 255) / 256;
    const int gW = (NN + 3) / 4;              // 4 waves/block, 1 node/wave
    const int nX4 = NN * 256 / 4;

    // CSR build
    hipMemsetAsync(cursor, 0, (size_t)NN * 4, stream);
    hist_kernel<<<gE, 256, 0, stream>>>(e_dst, cursor, NE);
    scan_kernel<<<1, 1024, 0, stream>>>(cursor, row_ptr, cursor, NN);
    fill_kernel<<<gE, 256, 0, stream>>>(e_src, e_dst, cursor, csr_src, NE);

    // casts
    cast4_kernel<<<(nX4 + 255) / 256, 256, 0, stream>>>(x, xb, nX4);
    castW_kernel<<<(256 * 256 + 256 * 64 + 255) / 256, 256, 0, stream>>>(W1, W2, w1t, w2t);

    // layer 1
    gemm_att1_kernel<<<(NN + 127) / 128, 512, 0, stream>>>(xb, w1t, att_s1, att_d1,
                                                           h1b, as1, ad1, NN);
    agg1_kernel<<<gW, 256, 0, stream>>>(h1b, as1, ad1, row_ptr, csr_src, b1, hb, NN);

    // layer 2
    gemm_att2_kernel<<<(NN + 255) / 256, 256, 0, stream>>>(hb, w2t, att_s2, att_d2,
                                                           h2b, as2, ad2, NN);
    agg2_kernel<<<gW, 256, 0, stream>>>(h2b, as2, ad2, row_ptr, csr_src, b2, out, NN);
}

// Round 6
// 198.925 us; speedup vs baseline: 1.7913x; 1.0161x over previous
//
#include <hip/hip_runtime.h>
#include <hip/hip_bf16.h>
#include <math.h>

// ---------------------------------------------------------------------------
// Two-layer GAT. bf16 storage + MFMA GEMMs (fp32 accum), attention scores
// fused into GEMM epilogues, CSR gather aggregation with 8x unrolled edge loop.
// Pipeline (8 dispatches):
//   prep (zero cursor + W1/W2 transpose-cast) -> hist -> scan -> fill   (CSR)
//   gemm_att1 (fp32 x direct; h1b + a_s1/a_d1) -> agg1 -> hb
//   gemm_att2 (h2b + a_s2/a_d2) -> agg2 -> out
// Softmax max-subtraction skipped (shift-invariant, |logits| ~ O(1)).
// ---------------------------------------------------------------------------

#define NN 30000
#define NE 480000

typedef __attribute__((ext_vector_type(8))) short bf16x8;
typedef __attribute__((ext_vector_type(4))) float f32x4;

static constexpr size_t au(size_t x) { return (x + 255) & ~(size_t)255; }

static constexpr size_t SZ_H1B = (size_t)NN * 256 * 2;
static constexpr size_t SZ_HB  = (size_t)NN * 256 * 2;
static constexpr size_t SZ_H2B = (size_t)NN * 64 * 2;
static constexpr size_t SZ_W1T = 256 * 256 * 2;
static constexpr size_t SZ_W2T = 64 * 256 * 2;
static constexpr size_t SZ_AS1 = (size_t)NN * 4 * 4;
static constexpr size_t SZ_AS2 = (size_t)NN * 4;
static constexpr size_t SZ_ROW = (size_t)(NN + 1) * 4;
static constexpr size_t SZ_CUR = (size_t)NN * 4;
static constexpr size_t SZ_CSR = (size_t)NE * 4;

static constexpr size_t OFF_H1B = 0;
static constexpr size_t OFF_HB  = OFF_H1B + au(SZ_H1B);
static constexpr size_t OFF_H2B = OFF_HB  + au(SZ_HB);
static constexpr size_t OFF_W1T = OFF_H2B + au(SZ_H2B);
static constexpr size_t OFF_W2T = OFF_W1T + au(SZ_W1T);
static constexpr size_t OFF_AS1 = OFF_W2T + au(SZ_W2T);
static constexpr size_t OFF_AD1 = OFF_AS1 + au(SZ_AS1);
static constexpr size_t OFF_AS2 = OFF_AD1 + au(SZ_AS1);
static constexpr size_t OFF_AD2 = OFF_AS2 + au(SZ_AS2);
static constexpr size_t OFF_ROW = OFF_AD2 + au(SZ_AS2);
static constexpr size_t OFF_CUR = OFF_ROW + au(SZ_ROW);
static constexpr size_t OFF_CSR = OFF_CUR + au(SZ_CUR);

__device__ __forceinline__ float lrelu(float x) { return x > 0.f ? x : 0.2f * x; }
__device__ __forceinline__ float elu1(float x)  { return x > 0.f ? x : expm1f(x); }

__device__ __forceinline__ float bf2f(ushort u) {
    union { unsigned i; float f; } v; v.i = ((unsigned)u) << 16; return v.f;
}
__device__ __forceinline__ ushort f2bf(float f) {   // round-to-nearest-even
    union { float f; unsigned i; } v; v.f = f;
    unsigned x = v.i;
    return (ushort)((x + 0x7FFFu + ((x >> 16) & 1u)) >> 16);
}

// ---------------- prep: zero cursor + transpose-cast W1/W2 ----------------
// grid covers 256*256 + 256*64 = 81920 >= NN; all writes independent.

__global__ __launch_bounds__(256) void prep_kernel(const float* __restrict__ W1,
                                                   const float* __restrict__ W2,
                                                   ushort* __restrict__ w1t,
                                                   ushort* __restrict__ w2t,
                                                   int* __restrict__ cursor) {
    int i = blockIdx.x * 256 + threadIdx.x;
    if (i < NN) cursor[i] = 0;
    if (i < 256 * 256) {
        int r = i >> 8, c = i & 255;
        w1t[c * 256 + r] = f2bf(W1[i]);
    } else {
        int j = i - 256 * 256;
        if (j < 256 * 64) {
            int r = j >> 6, c = j & 63;
            w2t[c * 256 + r] = f2bf(W2[j]);
        }
    }
}

// ---------------- CSR build ----------------

__global__ __launch_bounds__(256) void hist_kernel(const int* __restrict__ dst,
                                                   int* __restrict__ counts, int e) {
    int i = blockIdx.x * 256 + threadIdx.x;
    if (i < e) atomicAdd(&counts[dst[i]], 1);
}

// single-block single-pass exclusive scan: counts -> row_ptr[0..n] and cursor copy.
__global__ __launch_bounds__(1024) void scan_kernel(const int* __restrict__ counts,
                                                    int* __restrict__ row_ptr,
                                                    int* __restrict__ cursor, int n) {
    constexpr int CH = 30;
    __shared__ int wsum[16];
    const int tid = threadIdx.x, lane = tid & 63, wid = tid >> 6;
    const int base = tid * CH;
    int v[CH];
    int tot = 0;
#pragma unroll
    for (int j = 0; j < CH; ++j) {
        int i = base + j;
        v[j] = (i < n) ? counts[i] : 0;
        tot += v[j];
    }
    int x = tot;
#pragma unroll
    for (int off = 1; off < 64; off <<= 1) {
        int t = __shfl_up(x, off, 64);
        if (lane >= off) x += t;
    }
    if (lane == 63) wsum[wid] = x;
    __syncthreads();
    int wbase = 0;
    for (int w = 0; w < wid; ++w) wbase += wsum[w];
    int run = wbase + x - tot;               // exclusive prefix for this thread
#pragma unroll
    for (int j = 0; j < CH; ++j) {
        int i = base + j;
        if (i < n) { row_ptr[i] = run; cursor[i] = run; }
        run += v[j];
    }
    if (tid == 1023) row_ptr[n] = run;
}

__global__ __launch_bounds__(256) void fill_kernel(const int* __restrict__ src,
                                                   const int* __restrict__ dst,
                                                   int* __restrict__ cursor,
                                                   int* __restrict__ csr_src, int e) {
    int i = blockIdx.x * 256 + threadIdx.x;
    if (i < e) {
        int pos = atomicAdd(&cursor[dst[i]], 1);
        csr_src[pos] = src[i];
    }
}

// ---------------- GEMM1 + fused att1 ----------------
// C[M,256] = cast_bf16(X[M,256]) @ BT[256,256]^T. X is fp32, converted to bf16
// fragments in-register (same RNE rounding as a separate cast pass).
// 512 threads (wm 0..1 x wn 0..3), block tile 128x256. Epilogue computes
// a_s/a_d from the fp32 accumulators (in-wave shfl + LDS combine).
// Fragment layout (verified): A row=lane&15, k=(lane>>4)*8+j; C/D col=lane&15,
// row=(lane>>4)*4+reg.

__global__ __launch_bounds__(512)
void gemm_att1_kernel(const float* __restrict__ X, const ushort* __restrict__ BT,
                      const float* __restrict__ att_s, const float* __restrict__ att_d,
                      ushort* __restrict__ C, float* __restrict__ a_s,
                      float* __restrict__ a_d, int M) {
    constexpr int K = 256, N = 256;
    __shared__ float s_s[128 * 4], s_d[128 * 4];
    const int lane = threadIdx.x & 63;
    const int wid  = threadIdx.x >> 6;
    const int wm = wid >> 2, wn = wid & 3;
    const int r  = lane & 15;
    const int kq = lane >> 4;
    const long row0  = (long)blockIdx.x * 128;
    const long rbase = row0 + wm * 64;
    const int  col0  = wn * 64;

    f32x4 acc[4][4] = {};
#pragma unroll 2
    for (int ks = 0; ks < K / 32; ++ks) {
        const int kb = ks * 32 + kq * 8;
        bf16x8 bfr[4];
#pragma unroll
        for (int n = 0; n < 4; ++n)
            bfr[n] = *(const bf16x8*)(BT + (long)(col0 + n * 16 + r) * K + kb);
#pragma unroll
        for (int m = 0; m < 4; ++m) {
            long rr = rbase + m * 16 + r; if (rr >= M) rr = M - 1;
            const float* xp = X + rr * (long)K + kb;
            f32x4 x0 = *(const f32x4*)xp;
            f32x4 x1 = *(const f32x4*)(xp + 4);
            bf16x8 afr;
            afr[0] = (short)f2bf(x0[0]); afr[1] = (short)f2bf(x0[1]);
            afr[2] = (short)f2bf(x0[2]); afr[3] = (short)f2bf(x0[3]);
            afr[4] = (short)f2bf(x1[0]); afr[5] = (short)f2bf(x1[1]);
            afr[6] = (short)f2bf(x1[2]); afr[7] = (short)f2bf(x1[3]);
#pragma unroll
            for (int n = 0; n < 4; ++n)
                acc[m][n] = __builtin_amdgcn_mfma_f32_16x16x32_bf16(afr, bfr[n], acc[m][n], 0, 0, 0);
        }
    }
    // C (h1b) store
#pragma unroll
    for (int m = 0; m < 4; ++m)
#pragma unroll
        for (int reg = 0; reg < 4; ++reg) {
            long rr = rbase + m * 16 + kq * 4 + reg;
            if (rr < M) {
                ushort* cp = C + rr * (long)N + col0 + r;
#pragma unroll
                for (int n = 0; n < 4; ++n) cp[n * 16] = f2bf(acc[m][n][reg]);
            }
        }
    // fused attention scores (head == wn)
    float aws[4], awd[4];
#pragma unroll
    for (int n = 0; n < 4; ++n) {
        aws[n] = att_s[col0 + n * 16 + r];
        awd[n] = att_d[col0 + n * 16 + r];
    }
#pragma unroll
    for (int m = 0; m < 4; ++m)
#pragma unroll
        for (int reg = 0; reg < 4; ++reg) {
            float ps = acc[m][0][reg] * aws[0] + acc[m][1][reg] * aws[1]
                     + acc[m][2][reg] * aws[2] + acc[m][3][reg] * aws[3];
            float pd = acc[m][0][reg] * awd[0] + acc[m][1][reg] * awd[1]
                     + acc[m][2][reg] * awd[2] + acc[m][3][reg] * awd[3];
#pragma unroll
            for (int off = 1; off < 16; off <<= 1) {
                ps += __shfl_xor(ps, off, 64);
                pd += __shfl_xor(pd, off, 64);
            }
            if (r == 0) {
                int rl = wm * 64 + m * 16 + kq * 4 + reg;
                s_s[rl * 4 + wn] = ps;
                s_d[rl * 4 + wn] = pd;
            }
        }
    __syncthreads();
    int t = threadIdx.x;                     // 512 = 128 rows x 4 heads
    long row = row0 + (t >> 2);
    if (row < M) {
        a_s[row * 4 + (t & 3)] = s_s[t];
        a_d[row * 4 + (t & 3)] = s_d[t];
    }
}

// ---------------- GEMM2 + fused att2 ----------------

__global__ __launch_bounds__(256)
void gemm_att2_kernel(const ushort* __restrict__ A, const ushort* __restrict__ BT,
                      const float* __restrict__ att_s, const float* __restrict__ att_d,
                      ushort* __restrict__ C, float* __restrict__ a_s,
                      float* __restrict__ a_d, int M) {
    constexpr int K = 256, N = 64;
    const int lane = threadIdx.x & 63;
    const int wm   = threadIdx.x >> 6;
    const int r  = lane & 15;
    const int kq = lane >> 4;
    const long rbase = (long)blockIdx.x * 256 + wm * 64;

    f32x4 acc[4][4] = {};
#pragma unroll 2
    for (int ks = 0; ks < K / 32; ++ks) {
        const int kb = ks * 32 + kq * 8;
        bf16x8 bfr[4];
#pragma unroll
        for (int n = 0; n < 4; ++n)
            bfr[n] = *(const bf16x8*)(BT + (long)(n * 16 + r) * K + kb);
#pragma unroll
        for (int m = 0; m < 4; ++m) {
            long rr = rbase + m * 16 + r; if (rr >= M) rr = M - 1;
            bf16x8 afr = *(const bf16x8*)(A + rr * (long)K + kb);
#pragma unroll
            for (int n = 0; n < 4; ++n)
                acc[m][n] = __builtin_amdgcn_mfma_f32_16x16x32_bf16(afr, bfr[n], acc[m][n], 0, 0, 0);
        }
    }
#pragma unroll
    for (int m = 0; m < 4; ++m)
#pragma unroll
        for (int reg = 0; reg < 4; ++reg) {
            long rr = rbase + m * 16 + kq * 4 + reg;
            if (rr < M) {
                ushort* cp = C + rr * (long)N + r;
#pragma unroll
                for (int n = 0; n < 4; ++n) cp[n * 16] = f2bf(acc[m][n][reg]);
            }
        }
    float aws[4], awd[4];
#pragma unroll
    for (int n = 0; n < 4; ++n) {
        aws[n] = att_s[n * 16 + r];
        awd[n] = att_d[n * 16 + r];
    }
#pragma unroll
    for (int m = 0; m < 4; ++m)
#pragma unroll
        for (int reg = 0; reg < 4; ++reg) {
            float ps = acc[m][0][reg] * aws[0] + acc[m][1][reg] * aws[1]
                     + acc[m][2][reg] * aws[2] + acc[m][3][reg] * aws[3];
            float pd = acc[m][0][reg] * awd[0] + acc[m][1][reg] * awd[1]
                     + acc[m][2][reg] * awd[2] + acc[m][3][reg] * awd[3];
#pragma unroll
            for (int off = 1; off < 16; off <<= 1) {
                ps += __shfl_xor(ps, off, 64);
                pd += __shfl_xor(pd, off, 64);
            }
            if (r == 0) {
                long row = rbase + m * 16 + kq * 4 + reg;
                if (row < M) { a_s[row] = ps; a_d[row] = pd; }
            }
        }
}

// ---------------- aggregation (one wave per dst node, 8x unrolled) ----------

__global__ __launch_bounds__(256) void agg1_kernel(const ushort* __restrict__ h1b,
                                                   const float* __restrict__ a_s,
                                                   const float* __restrict__ a_d,
                                                   const int* __restrict__ row_ptr,
                                                   const int* __restrict__ csr_src,
                                                   const float* __restrict__ b1,
                                                   ushort* __restrict__ hb, int n_nodes) {
    const int lane = threadIdx.x & 63;
    const int n = blockIdx.x * 4 + (threadIdx.x >> 6);
    if (n >= n_nodes) return;
    const int head = lane >> 4;
    const float ad = a_d[(size_t)n * 4 + head];
    float acc0, acc1, acc2, acc3, ws;
    {   // self loop
        float w = __expf(lrelu(a_s[(size_t)n * 4 + head] + ad));
        ushort4 hv = *(const ushort4*)(h1b + (size_t)n * 256 + 4 * lane);
        acc0 = w * bf2f(hv.x); acc1 = w * bf2f(hv.y);
        acc2 = w * bf2f(hv.z); acc3 = w * bf2f(hv.w);
        ws = w;
    }
    int e = row_ptr[n];
    const int end = row_ptr[n + 1];
    for (; e + 8 <= end; e += 8) {
        int s[8];
#pragma unroll
        for (int j = 0; j < 8; ++j) s[j] = csr_src[e + j];
        float q[8];
        ushort4 hv[8];
#pragma unroll
        for (int j = 0; j < 8; ++j) {
            q[j] = a_s[(size_t)s[j] * 4 + head];
            hv[j] = *(const ushort4*)(h1b + (size_t)s[j] * 256 + 4 * lane);
        }
#pragma unroll
        for (int j = 0; j < 8; ++j) {
            float w = __expf(lrelu(q[j] + ad));
            acc0 = fmaf(w, bf2f(hv[j].x), acc0);
            acc1 = fmaf(w, bf2f(hv[j].y), acc1);
            acc2 = fmaf(w, bf2f(hv[j].z), acc2);
            acc3 = fmaf(w, bf2f(hv[j].w), acc3);
            ws += w;
        }
    }
    for (; e + 4 <= end; e += 4) {
        int s[4];
#pragma unroll
        for (int j = 0; j < 4; ++j) s[j] = csr_src[e + j];
        float q[4];
        ushort4 hv[4];
#pragma unroll
        for (int j = 0; j < 4; ++j) {
            q[j] = a_s[(size_t)s[j] * 4 + head];
            hv[j] = *(const ushort4*)(h1b + (size_t)s[j] * 256 + 4 * lane);
        }
#pragma unroll
        for (int j = 0; j < 4; ++j) {
            float w = __expf(lrelu(q[j] + ad));
            acc0 = fmaf(w, bf2f(hv[j].x), acc0);
            acc1 = fmaf(w, bf2f(hv[j].y), acc1);
            acc2 = fmaf(w, bf2f(hv[j].z), acc2);
            acc3 = fmaf(w, bf2f(hv[j].w), acc3);
            ws += w;
        }
    }
    for (; e < end; ++e) {
        int s = csr_src[e];
        float w = __expf(lrelu(a_s[(size_t)s * 4 + head] + ad));
        ushort4 hv = *(const ushort4*)(h1b + (size_t)s * 256 + 4 * lane);
        acc0 = fmaf(w, bf2f(hv.x), acc0); acc1 = fmaf(w, bf2f(hv.y), acc1);
        acc2 = fmaf(w, bf2f(hv.z), acc2); acc3 = fmaf(w, bf2f(hv.w), acc3);
        ws += w;
    }
    float4 bv = *(const float4*)(b1 + 4 * lane);
    float inv = 1.f / ws;
    ushort4 o;
    o.x = f2bf(elu1(acc0 * inv + bv.x));
    o.y = f2bf(elu1(acc1 * inv + bv.y));
    o.z = f2bf(elu1(acc2 * inv + bv.z));
    o.w = f2bf(elu1(acc3 * inv + bv.w));
    *(ushort4*)(hb + (size_t)n * 256 + 4 * lane) = o;
}

__global__ __launch_bounds__(256) void agg2_kernel(const ushort* __restrict__ h2b,
                                                   const float* __restrict__ a_s,
                                                   const float* __restrict__ a_d,
                                                   const int* __restrict__ row_ptr,
                                                   const int* __restrict__ csr_src,
                                                   const float* __restrict__ b2,
                                                   float* __restrict__ out, int n_nodes) {
    const int lane = threadIdx.x & 63;
    const int n = blockIdx.x * 4 + (threadIdx.x >> 6);
    if (n >= n_nodes) return;
    const float ad = a_d[n];
    float w0 = __expf(lrelu(a_s[n] + ad));
    float acc = w0 * bf2f(h2b[(size_t)n * 64 + lane]);
    float ws = w0;
    int e = row_ptr[n];
    const int end = row_ptr[n + 1];
    for (; e + 8 <= end; e += 8) {
        int s[8];
#pragma unroll
        for (int j = 0; j < 8; ++j) s[j] = csr_src[e + j];
        float q[8];
        ushort hv[8];
#pragma unroll
        for (int j = 0; j < 8; ++j) {
            q[j] = a_s[s[j]];
            hv[j] = h2b[(size_t)s[j] * 64 + lane];
        }
#pragma unroll
        for (int j = 0; j < 8; ++j) {
            float w = __expf(lrelu(q[j] + ad));
            acc = fmaf(w, bf2f(hv[j]), acc);
            ws += w;
        }
    }
    for (; e < end; ++e) {
        int s = csr_src[e];
        float we = __expf(lrelu(a_s[s] + ad));
        acc = fmaf(we, bf2f(h2b[(size_t)s * 64 + lane]), acc);
        ws += we;
    }
    out[(size_t)n * 64 + lane] = acc / ws + b2[lane];
}

// ---------------- launch ----------------

extern "C" void kernel_launch(void* const* d_in, const int* in_sizes, int n_in,
                              void* d_out, int out_size, void* d_ws, size_t ws_size,
                              hipStream_t stream) {
    const float* x      = (const float*)d_in[0];
    const int*   ei     = (const int*)d_in[1];    // [2, NE] int32
    const float* W1     = (const float*)d_in[2];
    const float* att_s1 = (const float*)d_in[3];
    const float* att_d1 = (const float*)d_in[4];
    const float* b1     = (const float*)d_in[5];
    const float* W2     = (const float*)d_in[6];
    const float* att_s2 = (const float*)d_in[7];
    const float* att_d2 = (const float*)d_in[8];
    const float* b2     = (const float*)d_in[9];
    float* out = (float*)d_out;

    char* ws = (char*)d_ws;
    ushort* h1b   = (ushort*)(ws + OFF_H1B);
    ushort* hb    = (ushort*)(ws + OFF_HB);
    ushort* h2b   = (ushort*)(ws + OFF_H2B);
    ushort* w1t   = (ushort*)(ws + OFF_W1T);
    ushort* w2t   = (ushort*)(ws + OFF_W2T);
    float* as1    = (float*)(ws + OFF_AS1);
    float* ad1    = (float*)(ws + OFF_AD1);
    float* as2    = (float*)(ws + OFF_AS2);
    float* ad2    = (float*)(ws + OFF_AD2);
    int* row_ptr  = (int*)(ws + OFF_ROW);
    int* cursor   = (int*)(ws + OFF_CUR);
    int* csr_src  = (int*)(ws + OFF_CSR);

    const int* e_src = ei;
    const int* e_dst = ei + NE;

    const int gE = (NE + 255) / 256;
    const int gW = (NN + 3) / 4;              // 4 waves/block, 1 node/wave

    // prep (zero cursor + W casts), then CSR build
    prep_kernel<<<(256 * 256 + 256 * 64 + 255) / 256, 256, 0, stream>>>(W1, W2, w1t, w2t, cursor);
    hist_kernel<<<gE, 256, 0, stream>>>(e_dst, cursor, NE);
    scan_kernel<<<1, 1024, 0, stream>>>(cursor, row_ptr, cursor, NN);
    fill_kernel<<<gE, 256, 0, stream>>>(e_src, e_dst, cursor, csr_src, NE);

    // layer 1
    gemm_att1_kernel<<<(NN + 127) / 128, 512, 0, stream>>>(x, w1t, att_s1, att_d1,
                                                           h1b, as1, ad1, NN);
    agg1_kernel<<<gW, 256, 0, stream>>>(h1b, as1, ad1, row_ptr, csr_src, b1, hb, NN);

    // layer 2
    gemm_att2_kernel<<<(NN + 255) / 256, 256, 0, stream>>>(hb, w2t, att_s2, att_d2,
                                                           h2b, as2, ad2, NN);
    agg2_kernel<<<gW, 256, 0, stream>>>(h2b, as2, ad2, row_ptr, csr_src, b2, out, NN);
}